// Round 9
// baseline (4441.426 us; speedup 1.0000x reference)
//
#include <hip/hip_runtime.h>

#define TT 365
#define BB 512
#define DD 16
#define HH 256
#define SS 32

typedef __attribute__((ext_vector_type(8))) short short8;
typedef __attribute__((ext_vector_type(4))) float f32x4;
typedef unsigned long long u64;

__device__ __host__ inline short f2bf(float f){
  union { float f; unsigned u; } v; v.f = f;
  unsigned r = v.u + 0x7FFFu + ((v.u >> 16) & 1u);
  return (short)(r >> 16);
}
__device__ inline float sigm(float x){ return 1.0f/(1.0f+__expf(-x)); }
__device__ inline float tanhx(float x){ return 2.0f/(1.0f+__expf(-2.0f*x)) - 1.0f; }

// A-fragment address (shorts) in an 8KB K=256 region for mfma_16x16x32 A-layout.
__device__ inline int fragAddr(int k, int m){
  return ((k>>5)*512) + ((((k&31)>>3)*16 + m)*8) + (k&7);
}

// pack 2 bf16 + 32-bit step tag into one u64 (value-tagged exchange word)
__device__ inline u64 pack2(float a, float b, unsigned tag){
  unsigned lo = (unsigned)(unsigned short)f2bf(a)
              | ((unsigned)(unsigned short)f2bf(b) << 16);
  return (u64)lo | ((u64)tag << 32);
}

// ---------------- prep kernels ----------------
__global__ void prep_weights(const float* __restrict__ Wih0, const float* __restrict__ Whh0,
                             const float* __restrict__ Wih1, const float* __restrict__ Whh1,
                             short* __restrict__ Wb0, short* __restrict__ Wb1)
{
  int idx = blockIdx.x*blockDim.x + threadIdx.x;
  const int n0 = 16*36*512;
  const int n1 = 16*64*512;
  if (idx < n0){
    int frag = idx >> 9, pos = idx & 511;
    int lane = pos >> 3, jj = pos & 7;
    int slot = frag / 36, rem = frag % 36;
    int ks = rem >> 2, nt = rem & 3;
    int n = nt*256 + slot*16 + (lane & 15);
    float v = 0.0f;
    if (ks == 0){
      int k32 = (lane>>4)*8 + jj;
      if (k32 < 16) v = Wih0[n*16 + k32];
    } else {
      int k = (ks-1)*32 + (lane>>4)*8 + jj;
      v = Whh0[n*256 + k];
    }
    Wb0[idx] = f2bf(v);
  } else if (idx < n0 + n1){
    int e = idx - n0;
    int frag = e >> 9, pos = e & 511;
    int lane = pos >> 3, jj = pos & 7;
    int slot = frag >> 6, rem = frag & 63;
    int ks = rem >> 2, nt = rem & 3;
    int n = nt*256 + slot*16 + (lane & 15);
    int k = ks*32 + (lane>>4)*8 + jj;
    float v = (k < 256) ? Wih1[n*256 + k] : Whh1[n*256 + (k-256)];
    Wb1[e] = f2bf(v);
  }
}

__global__ void prep_h0(const float* __restrict__ xs, const float* __restrict__ Ws,
                        const float* __restrict__ bs, float* __restrict__ h0init)
{
  int i = blockIdx.x*blockDim.x + threadIdx.x;
  int b = i >> 8, jj = i & 255;
  float s = bs[jj];
  const float* xr = xs + b*SS;
  const float* wr = Ws + jj*SS;
#pragma unroll
  for (int q=0;q<SS;++q) s += xr[q]*wr[q];
  h0init[i] = s;
}

__global__ void prep_bias(const float* __restrict__ a0, const float* __restrict__ a1,
                          const float* __restrict__ a2, const float* __restrict__ a3,
                          float* __restrict__ b0o, float* __restrict__ b1o)
{
  int i = threadIdx.x + blockIdx.x*blockDim.x;
  if (i < 1024) b0o[i] = a0[i] + a1[i];
  else if (i < 2048) b1o[i-1024] = a2[i-1024] + a3[i-1024];
}

__global__ void prep_zero(float* __restrict__ out)
{
  int i = blockIdx.x*blockDim.x + threadIdx.x;
  if (i < BB*TT) out[i] = 0.0f;
}

// ---------------- persistent fused LSTM ----------------
// 128 blocks x 256 threads; g = bid&31 (16 batch rows), c = bid>>5 (64 hidden cols).
// Weights register/AGPR-resident. Lag pipeline: superstep s = L0@t=s + L1@t=s-1.
// Exchange: value-tagged ring words (2 bf16 + step tag per u64).
//   publish = relaxed agent-scope atomic store (coalescing write-through; r6/r8-proven)
//   poll    = per iteration: ONE acquire load per thread (emits buffer_inv ->
//             fresh L1/L2; r4-proven) + PLAIN volatile dwordx2 loads of missing
//             words + register tag check. Zero RMWs on the data path (r8's
//             765 MB WRITE signature showed atomic loads lower to RMWs).
// No flags, no fences, no drains; 2 barriers/step. 4-slot ring causality and
// 0xAA-poison safety as in r8 (tags 1..366 unique, poison never matches).
__global__ __launch_bounds__(256, 1) void lstm_fused(
    const short* __restrict__ Wb0, const short* __restrict__ Wb1,
    const float* __restrict__ h0i, const float* __restrict__ b0c,
    const float* __restrict__ b1c, const float* __restrict__ x,
    const float* __restrict__ Wo, const float* __restrict__ bo,
    u64* __restrict__ ring0, u64* __restrict__ ring1,
    float* __restrict__ out)
{
  __shared__ alignas(16) short AX[512];     // x_t frags, K=32 (k>=16 zero)
  __shared__ alignas(16) short AH0[4096];   // h0[t-1] frags, K=256
  __shared__ alignas(16) short AH1[4096];   // h1[t-2] frags, K=256
  __shared__ float outacc[16][4];
  __shared__ float outLDS[TT][16];

  const int tid  = threadIdx.x;
  const int w    = tid >> 6;
  const int lane = tid & 63;
  const int col16= lane & 15;
  const int quad = lane >> 4;
  const int c    = blockIdx.x >> 5;
  const int g    = blockIdx.x & 31;
  const int rowbase = g * 16;
  const int slot = c*4 + w;
  const int colg = slot*16 + col16;

  // ---- register-resident weight fragments ----
  short8 F0[36], F1[64];
  {
    const short8* p0 = (const short8*)Wb0 + slot*36*64 + lane;
#pragma unroll
    for (int f=0; f<36; ++f) F0[f] = p0[f*64];
    const short8* p1 = (const short8*)Wb1 + slot*64*64 + lane;
#pragma unroll
    for (int f=0; f<64; ++f) F1[f] = p1[f*64];
  }
  float bia0[4], bia1[4];
#pragma unroll
  for (int nt=0; nt<4; ++nt){
    bia0[nt] = b0c[nt*256 + slot*16 + col16];
    bia1[nt] = b1c[nt*256 + slot*16 + col16];
  }
  const float wo = Wo[colg];

  // ---- init states + LDS ----
  float c0[4], c1[4];
#pragma unroll
  for (int r=0; r<4; ++r){
    c0[r] = h0i[(rowbase + quad*4 + r)*HH + colg];
    c1[r] = c0[r];
  }
  for (int i = tid; i < 4096; i += 256){
    int m = i >> 8, k = i & 255;
    short v = f2bf(h0i[(rowbase+m)*HH + k]);
    AH0[fragAddr(k,m)] = v;
    AH1[fragAddr(k,m)] = v;
  }
  {
    int m = tid >> 4, d = tid & 15;
    AX[fragAddr(d, m)]      = f2bf(x[(rowbase+m)*TT*DD + d]);
    AX[fragAddr(16 + d, m)] = 0;
  }
  __syncthreads();

  const f32x4 zero = {0.0f,0.0f,0.0f,0.0f};

  for (int s=0; s<=TT; ++s){
    const bool doL0 = (s < TT);
    const bool doL1 = (s >= 1);

    // prefetch x_{s+1} (hidden under MFMAs)
    float xf = 0.0f;
    if (s+1 < TT){
      int m = tid >> 4, d = tid & 15;
      xf = x[(rowbase+m)*TT*DD + (s+1)*DD + d];
    }

    // ---- MFMA phase ----
    f32x4 acc0[4], acc1[4];
#pragma unroll
    for (int nt=0; nt<4; ++nt){ acc0[nt]=zero; acc1[nt]=zero; }
    if (doL0){
      short8 a = *(const short8*)(AX + lane*8);
#pragma unroll
      for (int nt=0; nt<4; ++nt)
        acc0[nt] = __builtin_amdgcn_mfma_f32_16x16x32_bf16(a, F0[nt], acc0[nt], 0,0,0);
    }
#pragma unroll
    for (int ks=0; ks<8; ++ks){
      short8 a = *(const short8*)(AH0 + ks*512 + lane*8);
      if (doL0){
#pragma unroll
        for (int nt=0; nt<4; ++nt)
          acc0[nt] = __builtin_amdgcn_mfma_f32_16x16x32_bf16(a, F0[(ks+1)*4+nt], acc0[nt], 0,0,0);
      }
      if (doL1){
#pragma unroll
        for (int nt=0; nt<4; ++nt)
          acc1[nt] = __builtin_amdgcn_mfma_f32_16x16x32_bf16(a, F1[ks*4+nt], acc1[nt], 0,0,0);
      }
    }
    if (doL1){
#pragma unroll
      for (int ks=0; ks<8; ++ks){
        short8 a = *(const short8*)(AH1 + ks*512 + lane*8);
#pragma unroll
        for (int nt=0; nt<4; ++nt)
          acc1[nt] = __builtin_amdgcn_mfma_f32_16x16x32_bf16(a, F1[32+ks*4+nt], acc1[nt], 0,0,0);
      }
    }

    // ---- L0 epilogue + immediate tagged publish (relaxed atomic stores) ----
    float h0v[4], h1v[4];
    if (doL0){
#pragma unroll
      for (int r=0; r<4; ++r){
        float iv = sigm (acc0[0][r] + bia0[0]);
        float fv = sigm (acc0[1][r] + bia0[1]);
        float gv = tanhx(acc0[2][r] + bia0[2]);
        float ov = sigm (acc0[3][r] + bia0[3]);
        float cc = fv*c0[r] + iv*gv;
        c0[r] = cc;
        h0v[r] = ov * tanhx(cc);
      }
      u64 base = (u64)(((s&3)*32+g)*256 + colg)*8 + quad*2;
      __hip_atomic_store(ring0 + base + 0, pack2(h0v[0], h0v[1], (unsigned)(s+1)),
                         __ATOMIC_RELAXED, __HIP_MEMORY_SCOPE_AGENT);
      __hip_atomic_store(ring0 + base + 1, pack2(h0v[2], h0v[3], (unsigned)(s+1)),
                         __ATOMIC_RELAXED, __HIP_MEMORY_SCOPE_AGENT);
    }
    // ---- L1 epilogue + tagged publish + out partial ----
    if (doL1){
      float pr[4];
#pragma unroll
      for (int r=0; r<4; ++r){
        float iv = sigm (acc1[0][r] + bia1[0]);
        float fv = sigm (acc1[1][r] + bia1[1]);
        float gv = tanhx(acc1[2][r] + bia1[2]);
        float ov = sigm (acc1[3][r] + bia1[3]);
        float cc = fv*c1[r] + iv*gv;
        c1[r] = cc;
        float h = ov * tanhx(cc);
        h1v[r] = h;
        pr[r] = h * wo;
      }
      u64 base = (u64)((((s-1)&3)*32+g)*256 + colg)*8 + quad*2;
      __hip_atomic_store(ring1 + base + 0, pack2(h1v[0], h1v[1], (unsigned)s),
                         __ATOMIC_RELAXED, __HIP_MEMORY_SCOPE_AGENT);
      __hip_atomic_store(ring1 + base + 1, pack2(h1v[2], h1v[3], (unsigned)s),
                         __ATOMIC_RELAXED, __HIP_MEMORY_SCOPE_AGENT);
#pragma unroll
      for (int m=1; m<16; m<<=1){
#pragma unroll
        for (int r=0; r<4; ++r) pr[r] += __shfl_xor(pr[r], m, 64);
      }
      if (col16 == 0){
#pragma unroll
        for (int r=0; r<4; ++r) outacc[quad*4 + r][w] = pr[r];
      }
    }

    __syncthreads();   // A: all LDS reads of this step done

    // own h into LDS frags; stage x_{s+1}; out partial for t=s-1
    if (doL0){
#pragma unroll
      for (int r=0; r<4; ++r) AH0[fragAddr(colg, quad*4 + r)] = f2bf(h0v[r]);
    }
    if (doL1 && s < TT){
#pragma unroll
      for (int r=0; r<4; ++r) AH1[fragAddr(colg, quad*4 + r)] = f2bf(h1v[r]);
    }
    if (s+1 < TT){
      int m = tid >> 4, d = tid & 15;
      AX[fragAddr(d, m)] = f2bf(xf);
    }
    if (doL1 && tid < 16)
      outLDS[s-1][tid] = outacc[tid][0] + outacc[tid][1] + outacc[tid][2] + outacc[tid][3];

    // ---- poll partner tagged words: acquire-inv + PLAIN volatile loads ----
    if (s < TT){
      const u64* r0b = ring0 + (u64)((s&3)*32+g)*2048;
      const u64* r1b = ring1 + (u64)(((s-1)&3)*32+g)*2048;
      const unsigned tag0 = (unsigned)(s+1);
      const unsigned tag1 = (unsigned)s;
      unsigned need0 = 0x3F, need1 = (s >= 1) ? 0x3F : 0;
      u64 w0v[6], w1v[6];
      int offs[6];
#pragma unroll
      for (int j=0; j<6; ++j){
        int i2 = tid + 256*j;                     // 0..1535
        int p   = (c + 1 + (i2>>9)) & 3;          // partner
        offs[j] = (p*64 + ((i2>>3)&63))*8 + ((i2>>1)&3)*2 + (i2&1);
      }
      while (need0 | need1){
        // refresh caches: one acquire load per thread (buffer_inv), value unused
        (void)__hip_atomic_load(r0b + (tid & 63), __ATOMIC_ACQUIRE, __HIP_MEMORY_SCOPE_AGENT);
#pragma unroll
        for (int j=0; j<6; ++j){
          if (need0 & (1u<<j)){
            u64 v = *(volatile const u64*)(r0b + offs[j]);   // plain coalesced load
            if ((unsigned)(v>>32) == tag0){ w0v[j] = v; need0 &= ~(1u<<j); }
          }
          if (need1 & (1u<<j)){
            u64 v = *(volatile const u64*)(r1b + offs[j]);
            if ((unsigned)(v>>32) == tag1){ w1v[j] = v; need1 &= ~(1u<<j); }
          }
        }
      }
#pragma unroll
      for (int j=0; j<6; ++j){
        int i2 = tid + 256*j;
        int p = (c + 1 + (i2>>9)) & 3;
        int k = p*64 + ((i2>>3)&63);
        int m = ((i2>>1)&3)*4 + (i2&1)*2;
        AH0[fragAddr(k, m)]   = (short)(w0v[j] & 0xFFFF);
        AH0[fragAddr(k, m+1)] = (short)((w0v[j] >> 16) & 0xFFFF);
        if (s >= 1){
          AH1[fragAddr(k, m)]   = (short)(w1v[j] & 0xFFFF);
          AH1[fragAddr(k, m+1)] = (short)((w1v[j] >> 16) & 0xFFFF);
        }
      }
    }
    __syncthreads();   // B: LDS ready for next superstep
  }

  // ---- final out accumulation (RMWs only here, off the critical loop) ----
  const float bos = bo[0];
  for (int i = tid; i < TT*16; i += 256){
    int t = i >> 4, row = i & 15;
    float v = outLDS[t][row];
    if (c == 0) v += bos;
    atomicAdd(&out[(rowbase + row)*TT + t], v);
  }
}

// ---------------- launch ----------------
extern "C" void kernel_launch(void* const* d_in, const int* in_sizes, int n_in,
                              void* d_out, int out_size, void* d_ws, size_t ws_size,
                              hipStream_t stream)
{
  const float* x    = (const float*)d_in[0];
  const float* xs   = (const float*)d_in[1];
  const float* Wih0 = (const float*)d_in[2];
  const float* Whh0 = (const float*)d_in[3];
  const float* bih0 = (const float*)d_in[4];
  const float* bhh0 = (const float*)d_in[5];
  const float* Wih1 = (const float*)d_in[6];
  const float* Whh1 = (const float*)d_in[7];
  const float* bih1 = (const float*)d_in[8];
  const float* bhh1 = (const float*)d_in[9];
  const float* Ws   = (const float*)d_in[10];
  const float* bs   = (const float*)d_in[11];
  const float* Wo   = (const float*)d_in[12];
  const float* bo   = (const float*)d_in[13];
  float* out = (float*)d_out;

  char* ws = (char*)d_ws;
  short*    Wb0   = (short*)(ws);                // 589824
  short*    Wb1   = (short*)(ws + 589824);       // 1048576 -> 1638400
  float*    h0i   = (float*)(ws + 1638400);      // 524288  -> 2162688
  float*    b0cp  = (float*)(ws + 2162688);      // 4096    -> 2166784
  float*    b1cp  = (float*)(ws + 2166784);      // 4096    -> 2170880
  u64*      ring0 = (u64*)(ws + 2170880);        // 2097152 -> 4268032
  u64*      ring1 = (u64*)(ws + 4268032);        // 2097152 -> 6365184 (~6.37 MB)

  int nswz = 16*36*512 + 16*64*512;
  hipLaunchKernelGGL(prep_weights, dim3((nswz+255)/256), dim3(256), 0, stream,
                     Wih0, Whh0, Wih1, Whh1, Wb0, Wb1);
  hipLaunchKernelGGL(prep_h0, dim3(512), dim3(256), 0, stream, xs, Ws, bs, h0i);
  hipLaunchKernelGGL(prep_bias, dim3(8), dim3(256), 0, stream, bih0, bhh0, bih1, bhh1, b0cp, b1cp);
  hipLaunchKernelGGL(prep_zero, dim3((BB*TT+255)/256), dim3(256), 0, stream, out);

  hipLaunchKernelGGL(lstm_fused, dim3(128), dim3(256), 0, stream,
                     Wb0, Wb1, h0i, b0cp, b1cp, x, Wo, bo,
                     ring0, ring1, out);
}

// Round 10
// 3585.532 us; speedup vs baseline: 1.2387x; 1.2387x over previous
//
#include <hip/hip_runtime.h>

#define TT 365
#define BB 512
#define DD 16
#define HH 256
#define SS 32

typedef __attribute__((ext_vector_type(8))) short short8;
typedef __attribute__((ext_vector_type(4))) float f32x4;
typedef unsigned long long u64;

__device__ __host__ inline short f2bf(float f){
  union { float f; unsigned u; } v; v.f = f;
  unsigned r = v.u + 0x7FFFu + ((v.u >> 16) & 1u);
  return (short)(r >> 16);
}
__device__ inline float sigm(float x){ return 1.0f/(1.0f+__expf(-x)); }
__device__ inline float tanhx(float x){ return 2.0f/(1.0f+__expf(-2.0f*x)) - 1.0f; }

// A-fragment address (shorts) in an 8KB K=256 region for mfma_16x16x32 A-layout.
__device__ inline int fragAddr(int k, int m){
  return ((k>>5)*512) + ((((k&31)>>3)*16 + m)*8) + (k&7);
}

// pack 2 bf16 + 32-bit step tag into one u64 (value-tagged exchange word)
__device__ inline u64 pack2(float a, float b, unsigned tag){
  unsigned lo = (unsigned)(unsigned short)f2bf(a)
              | ((unsigned)(unsigned short)f2bf(b) << 16);
  return (u64)lo | ((u64)tag << 32);
}

// ---------------- prep kernels ----------------
__global__ void prep_weights(const float* __restrict__ Wih0, const float* __restrict__ Whh0,
                             const float* __restrict__ Wih1, const float* __restrict__ Whh1,
                             short* __restrict__ Wb0, short* __restrict__ Wb1)
{
  int idx = blockIdx.x*blockDim.x + threadIdx.x;
  const int n0 = 16*36*512;
  const int n1 = 16*64*512;
  if (idx < n0){
    int frag = idx >> 9, pos = idx & 511;
    int lane = pos >> 3, jj = pos & 7;
    int slot = frag / 36, rem = frag % 36;
    int ks = rem >> 2, nt = rem & 3;
    int n = nt*256 + slot*16 + (lane & 15);
    float v = 0.0f;
    if (ks == 0){
      int k32 = (lane>>4)*8 + jj;
      if (k32 < 16) v = Wih0[n*16 + k32];
    } else {
      int k = (ks-1)*32 + (lane>>4)*8 + jj;
      v = Whh0[n*256 + k];
    }
    Wb0[idx] = f2bf(v);
  } else if (idx < n0 + n1){
    int e = idx - n0;
    int frag = e >> 9, pos = e & 511;
    int lane = pos >> 3, jj = pos & 7;
    int slot = frag >> 6, rem = frag & 63;
    int ks = rem >> 2, nt = rem & 3;
    int n = nt*256 + slot*16 + (lane & 15);
    int k = ks*32 + (lane>>4)*8 + jj;
    float v = (k < 256) ? Wih1[n*256 + k] : Whh1[n*256 + (k-256)];
    Wb1[e] = f2bf(v);
  }
}

__global__ void prep_h0(const float* __restrict__ xs, const float* __restrict__ Ws,
                        const float* __restrict__ bs, float* __restrict__ h0init)
{
  int i = blockIdx.x*blockDim.x + threadIdx.x;
  int b = i >> 8, jj = i & 255;
  float s = bs[jj];
  const float* xr = xs + b*SS;
  const float* wr = Ws + jj*SS;
#pragma unroll
  for (int q=0;q<SS;++q) s += xr[q]*wr[q];
  h0init[i] = s;
}

__global__ void prep_bias(const float* __restrict__ a0, const float* __restrict__ a1,
                          const float* __restrict__ a2, const float* __restrict__ a3,
                          float* __restrict__ b0o, float* __restrict__ b1o)
{
  int i = threadIdx.x + blockIdx.x*blockDim.x;
  if (i < 1024) b0o[i] = a0[i] + a1[i];
  else if (i < 2048) b1o[i-1024] = a2[i-1024] + a3[i-1024];
}

__global__ void prep_zero(float* __restrict__ out)
{
  int i = blockIdx.x*blockDim.x + threadIdx.x;
  if (i < BB*TT) out[i] = 0.0f;
}

// ---------------- persistent fused LSTM ----------------
// 128 blocks x 256 threads; g = bid&31 (16 batch rows), c = bid>>5 (64 hidden cols).
// Weights register/AGPR-resident. Lag pipeline: superstep s = L0@t=s + L1@t=s-1.
// Exchange: value-tagged ring words (2 bf16 + step tag per u64).
//   publish = relaxed agent-scope atomic store (r6/r8-proven to reach MALL)
//   poll    = PLAIN volatile u64 loads of the tagged words (per-instruction reads,
//             no atomics, no RMWs) + lane0-per-wave ACQUIRE escalation every 16
//             misses (buffer_inv -> guaranteed-fresh refetch; deadlock-proof).
// Atomic ops in the loop: publishes only (+rare escalation). 2 barriers/step.
// 4-slot ring causality and 0xAA-poison safety as r8 (tags 1..366 unique; the
// harness re-poisons d_ws before every launch, so no cross-launch stale tags).
__global__ __launch_bounds__(256, 1) void lstm_fused(
    const short* __restrict__ Wb0, const short* __restrict__ Wb1,
    const float* __restrict__ h0i, const float* __restrict__ b0c,
    const float* __restrict__ b1c, const float* __restrict__ x,
    const float* __restrict__ Wo, const float* __restrict__ bo,
    u64* __restrict__ ring0, u64* __restrict__ ring1,
    float* __restrict__ out)
{
  __shared__ alignas(16) short AX[512];     // x_t frags, K=32 (k>=16 zero)
  __shared__ alignas(16) short AH0[4096];   // h0[t-1] frags, K=256
  __shared__ alignas(16) short AH1[4096];   // h1[t-2] frags, K=256
  __shared__ float outacc[16][4];
  __shared__ float outLDS[TT][16];

  const int tid  = threadIdx.x;
  const int w    = tid >> 6;
  const int lane = tid & 63;
  const int col16= lane & 15;
  const int quad = lane >> 4;
  const int c    = blockIdx.x >> 5;
  const int g    = blockIdx.x & 31;
  const int rowbase = g * 16;
  const int slot = c*4 + w;
  const int colg = slot*16 + col16;

  // ---- register-resident weight fragments ----
  short8 F0[36], F1[64];
  {
    const short8* p0 = (const short8*)Wb0 + slot*36*64 + lane;
#pragma unroll
    for (int f=0; f<36; ++f) F0[f] = p0[f*64];
    const short8* p1 = (const short8*)Wb1 + slot*64*64 + lane;
#pragma unroll
    for (int f=0; f<64; ++f) F1[f] = p1[f*64];
  }
  float bia0[4], bia1[4];
#pragma unroll
  for (int nt=0; nt<4; ++nt){
    bia0[nt] = b0c[nt*256 + slot*16 + col16];
    bia1[nt] = b1c[nt*256 + slot*16 + col16];
  }
  const float wo = Wo[colg];

  // ---- init states + LDS ----
  float c0[4], c1[4];
#pragma unroll
  for (int r=0; r<4; ++r){
    c0[r] = h0i[(rowbase + quad*4 + r)*HH + colg];
    c1[r] = c0[r];
  }
  for (int i = tid; i < 4096; i += 256){
    int m = i >> 8, k = i & 255;
    short v = f2bf(h0i[(rowbase+m)*HH + k]);
    AH0[fragAddr(k,m)] = v;
    AH1[fragAddr(k,m)] = v;
  }
  {
    int m = tid >> 4, d = tid & 15;
    AX[fragAddr(d, m)]      = f2bf(x[(rowbase+m)*TT*DD + d]);
    AX[fragAddr(16 + d, m)] = 0;
  }
  __syncthreads();

  const f32x4 zero = {0.0f,0.0f,0.0f,0.0f};

  for (int s=0; s<=TT; ++s){
    const bool doL0 = (s < TT);
    const bool doL1 = (s >= 1);

    // prefetch x_{s+1} (hidden under MFMAs)
    float xf = 0.0f;
    if (s+1 < TT){
      int m = tid >> 4, d = tid & 15;
      xf = x[(rowbase+m)*TT*DD + (s+1)*DD + d];
    }

    // ---- MFMA phase ----
    f32x4 acc0[4], acc1[4];
#pragma unroll
    for (int nt=0; nt<4; ++nt){ acc0[nt]=zero; acc1[nt]=zero; }
    if (doL0){
      short8 a = *(const short8*)(AX + lane*8);
#pragma unroll
      for (int nt=0; nt<4; ++nt)
        acc0[nt] = __builtin_amdgcn_mfma_f32_16x16x32_bf16(a, F0[nt], acc0[nt], 0,0,0);
    }
#pragma unroll
    for (int ks=0; ks<8; ++ks){
      short8 a = *(const short8*)(AH0 + ks*512 + lane*8);
      if (doL0){
#pragma unroll
        for (int nt=0; nt<4; ++nt)
          acc0[nt] = __builtin_amdgcn_mfma_f32_16x16x32_bf16(a, F0[(ks+1)*4+nt], acc0[nt], 0,0,0);
      }
      if (doL1){
#pragma unroll
        for (int nt=0; nt<4; ++nt)
          acc1[nt] = __builtin_amdgcn_mfma_f32_16x16x32_bf16(a, F1[ks*4+nt], acc1[nt], 0,0,0);
      }
    }
    if (doL1){
#pragma unroll
      for (int ks=0; ks<8; ++ks){
        short8 a = *(const short8*)(AH1 + ks*512 + lane*8);
#pragma unroll
        for (int nt=0; nt<4; ++nt)
          acc1[nt] = __builtin_amdgcn_mfma_f32_16x16x32_bf16(a, F1[32+ks*4+nt], acc1[nt], 0,0,0);
      }
    }

    // ---- L0 epilogue + immediate tagged publish (relaxed atomic stores) ----
    float h0v[4], h1v[4];
    if (doL0){
#pragma unroll
      for (int r=0; r<4; ++r){
        float iv = sigm (acc0[0][r] + bia0[0]);
        float fv = sigm (acc0[1][r] + bia0[1]);
        float gv = tanhx(acc0[2][r] + bia0[2]);
        float ov = sigm (acc0[3][r] + bia0[3]);
        float cc = fv*c0[r] + iv*gv;
        c0[r] = cc;
        h0v[r] = ov * tanhx(cc);
      }
      u64 base = (u64)(((s&3)*32+g)*256 + colg)*8 + quad*2;
      __hip_atomic_store(ring0 + base + 0, pack2(h0v[0], h0v[1], (unsigned)(s+1)),
                         __ATOMIC_RELAXED, __HIP_MEMORY_SCOPE_AGENT);
      __hip_atomic_store(ring0 + base + 1, pack2(h0v[2], h0v[3], (unsigned)(s+1)),
                         __ATOMIC_RELAXED, __HIP_MEMORY_SCOPE_AGENT);
    }
    // ---- L1 epilogue + tagged publish + out partial ----
    if (doL1){
      float pr[4];
#pragma unroll
      for (int r=0; r<4; ++r){
        float iv = sigm (acc1[0][r] + bia1[0]);
        float fv = sigm (acc1[1][r] + bia1[1]);
        float gv = tanhx(acc1[2][r] + bia1[2]);
        float ov = sigm (acc1[3][r] + bia1[3]);
        float cc = fv*c1[r] + iv*gv;
        c1[r] = cc;
        float h = ov * tanhx(cc);
        h1v[r] = h;
        pr[r] = h * wo;
      }
      u64 base = (u64)((((s-1)&3)*32+g)*256 + colg)*8 + quad*2;
      __hip_atomic_store(ring1 + base + 0, pack2(h1v[0], h1v[1], (unsigned)s),
                         __ATOMIC_RELAXED, __HIP_MEMORY_SCOPE_AGENT);
      __hip_atomic_store(ring1 + base + 1, pack2(h1v[2], h1v[3], (unsigned)s),
                         __ATOMIC_RELAXED, __HIP_MEMORY_SCOPE_AGENT);
#pragma unroll
      for (int m=1; m<16; m<<=1){
#pragma unroll
        for (int r=0; r<4; ++r) pr[r] += __shfl_xor(pr[r], m, 64);
      }
      if (col16 == 0){
#pragma unroll
        for (int r=0; r<4; ++r) outacc[quad*4 + r][w] = pr[r];
      }
    }

    __syncthreads();   // A: all LDS reads of this step done

    // own h into LDS frags; stage x_{s+1}; out partial for t=s-1
    if (doL0){
#pragma unroll
      for (int r=0; r<4; ++r) AH0[fragAddr(colg, quad*4 + r)] = f2bf(h0v[r]);
    }
    if (doL1 && s < TT){
#pragma unroll
      for (int r=0; r<4; ++r) AH1[fragAddr(colg, quad*4 + r)] = f2bf(h1v[r]);
    }
    if (s+1 < TT){
      int m = tid >> 4, d = tid & 15;
      AX[fragAddr(d, m)] = f2bf(xf);
    }
    if (doL1 && tid < 16)
      outLDS[s-1][tid] = outacc[tid][0] + outacc[tid][1] + outacc[tid][2] + outacc[tid][3];

    // ---- poll partner tagged words: volatile loads + rare acquire escalation ----
    if (s < TT){
      const u64* r0b = ring0 + (u64)((s&3)*32+g)*2048;
      const u64* r1b = ring1 + (u64)(((s-1)&3)*32+g)*2048;
      const unsigned tag0 = (unsigned)(s+1);
      const unsigned tag1 = (unsigned)s;
      unsigned need0 = 0x3F, need1 = (s >= 1) ? 0x3F : 0;
      u64 w0v[6], w1v[6];
      int offs[6];
#pragma unroll
      for (int j=0; j<6; ++j){
        int i2 = tid + 256*j;                     // 0..1535
        int p   = (c + 1 + (i2>>9)) & 3;          // partner
        offs[j] = (p*64 + ((i2>>3)&63))*8 + ((i2>>1)&3)*2 + (i2&1);
      }
      unsigned spin = 0;
      while (__ballot((need0 | need1) != 0u)){
        // escalation: one acquire (buffer_inv) per wave every 16 misses --
        // guarantees progress even if volatile loads hit stale cache lines
        if (((spin++ & 15u) == 15u) && lane == 0)
          (void)__hip_atomic_load(r0b, __ATOMIC_ACQUIRE, __HIP_MEMORY_SCOPE_AGENT);
#pragma unroll
        for (int j=0; j<6; ++j){
          if (need0 & (1u<<j)){
            u64 v = *(volatile const u64*)(r0b + offs[j]);   // plain poll load
            if ((unsigned)(v>>32) == tag0){ w0v[j] = v; need0 &= ~(1u<<j); }
          }
          if (need1 & (1u<<j)){
            u64 v = *(volatile const u64*)(r1b + offs[j]);
            if ((unsigned)(v>>32) == tag1){ w1v[j] = v; need1 &= ~(1u<<j); }
          }
        }
      }
#pragma unroll
      for (int j=0; j<6; ++j){
        int i2 = tid + 256*j;
        int p = (c + 1 + (i2>>9)) & 3;
        int k = p*64 + ((i2>>3)&63);
        int m = ((i2>>1)&3)*4 + (i2&1)*2;
        AH0[fragAddr(k, m)]   = (short)(w0v[j] & 0xFFFF);
        AH0[fragAddr(k, m+1)] = (short)((w0v[j] >> 16) & 0xFFFF);
        if (s >= 1){
          AH1[fragAddr(k, m)]   = (short)(w1v[j] & 0xFFFF);
          AH1[fragAddr(k, m+1)] = (short)((w1v[j] >> 16) & 0xFFFF);
        }
      }
    }
    __syncthreads();   // B: LDS ready for next superstep
  }

  // ---- final out accumulation (RMWs only here, off the critical loop) ----
  const float bos = bo[0];
  for (int i = tid; i < TT*16; i += 256){
    int t = i >> 4, row = i & 15;
    float v = outLDS[t][row];
    if (c == 0) v += bos;
    atomicAdd(&out[(rowbase + row)*TT + t], v);
  }
}

// ---------------- launch ----------------
extern "C" void kernel_launch(void* const* d_in, const int* in_sizes, int n_in,
                              void* d_out, int out_size, void* d_ws, size_t ws_size,
                              hipStream_t stream)
{
  const float* x    = (const float*)d_in[0];
  const float* xs   = (const float*)d_in[1];
  const float* Wih0 = (const float*)d_in[2];
  const float* Whh0 = (const float*)d_in[3];
  const float* bih0 = (const float*)d_in[4];
  const float* bhh0 = (const float*)d_in[5];
  const float* Wih1 = (const float*)d_in[6];
  const float* Whh1 = (const float*)d_in[7];
  const float* bih1 = (const float*)d_in[8];
  const float* bhh1 = (const float*)d_in[9];
  const float* Ws   = (const float*)d_in[10];
  const float* bs   = (const float*)d_in[11];
  const float* Wo   = (const float*)d_in[12];
  const float* bo   = (const float*)d_in[13];
  float* out = (float*)d_out;

  char* ws = (char*)d_ws;
  short*    Wb0   = (short*)(ws);                // 589824
  short*    Wb1   = (short*)(ws + 589824);       // 1048576 -> 1638400
  float*    h0i   = (float*)(ws + 1638400);      // 524288  -> 2162688
  float*    b0cp  = (float*)(ws + 2162688);      // 4096    -> 2166784
  float*    b1cp  = (float*)(ws + 2166784);      // 4096    -> 2170880
  u64*      ring0 = (u64*)(ws + 2170880);        // 2097152 -> 4268032
  u64*      ring1 = (u64*)(ws + 4268032);        // 2097152 -> 6365184 (~6.37 MB)

  int nswz = 16*36*512 + 16*64*512;
  hipLaunchKernelGGL(prep_weights, dim3((nswz+255)/256), dim3(256), 0, stream,
                     Wih0, Whh0, Wih1, Whh1, Wb0, Wb1);
  hipLaunchKernelGGL(prep_h0, dim3(512), dim3(256), 0, stream, xs, Ws, bs, h0i);
  hipLaunchKernelGGL(prep_bias, dim3(8), dim3(256), 0, stream, bih0, bhh0, bih1, bhh1, b0cp, b1cp);
  hipLaunchKernelGGL(prep_zero, dim3((BB*TT+255)/256), dim3(256), 0, stream, out);

  hipLaunchKernelGGL(lstm_fused, dim3(128), dim3(256), 0, stream,
                     Wb0, Wb1, h0i, b0cp, b1cp, x, Wo, bo,
                     ring0, ring1, out);
}